// Round 6
// baseline (160.712 us; speedup 1.0000x reference)
//
#include <hip/hip_runtime.h>

#define CC 192
#define NN 16384
#define XST2 102  // kv Xs stride: 51 dw (odd) -> conflict-free b128 reads, 2-way b64 writes
#define SST2 66   // kv Ss/Vs stride: 33 dw (odd) -> conflict-free b128 reads
#define QXST 104  // kq Xs stride
#define QST 200   // kq SsT stride

typedef unsigned short u16;
typedef __attribute__((ext_vector_type(4))) float f32x4;
typedef __attribute__((ext_vector_type(8))) __bf16 bf16x8;
typedef __attribute__((ext_vector_type(8))) u16 u16x8;
typedef __attribute__((ext_vector_type(4))) u16 u16x4;

union FragU { u16x8 u; bf16x8 b; };

__device__ __forceinline__ u16 f2bf(float f) {
  union { float f; unsigned u; } x; x.f = f;
  return (u16)((x.u + 0x7FFFu + ((x.u >> 16) & 1u)) >> 16);  // RNE
}
__device__ __forceinline__ float bf2f(u16 h) {
  union { unsigned u; float f; } x; x.u = ((unsigned)h) << 16;
  return x.f;
}

// lgkmcnt(0) + raw barrier: LDS handoff WITHOUT draining vmcnt, so global
// prefetch loads issued before it stay in flight across the barrier.
__device__ __forceinline__ void lgkm_barrier() {
  asm volatile("s_waitcnt lgkmcnt(0)" ::: "memory");
  __builtin_amdgcn_s_barrier();
}

// ---------------- kv: pipelined K/V projections + ctx partials ----------------
// TN=64, 2 tiles/block, 8 rounds (t,pj,hf). Per round: issue W(r) frags (L2),
// cvt+ds_write X(r) (hw waits the HBM loads issued last round), issue X(r+1)
// HBM loads, lgkm-barrier (loads keep flying), MFMA, epilogue, lgkm-barrier.
// VGPR budget: acc48+cacc32+ksum12+xp24+wp72+misc ~= 230 < 256 cap at (256,2).
__global__ __launch_bounds__(256, 2)
void kv(const float* __restrict__ k, const float* __restrict__ v,
        const u16* __restrict__ Wb, const float* __restrict__ bk,
        const float* __restrict__ bv, float* __restrict__ part)
{
  __shared__ __align__(16) u16 Xs[64][XST2];       // 13.1 KB
  __shared__ __align__(16) u16 SV[2][192][SST2];   // 50.7 KB ([0]=Ss, [1]=Vs; Cs at end)

  const int b = blockIdx.y, blk = blockIdx.x;      // blk 0..127
  const int tid = threadIdx.x;
  const int lg = (tid >> 4) & 3, lc = tid & 15;
  const int wave = tid >> 6, e0 = wave * 48;
  const int sn = tid & 63, scg = wave;

  const float* xb[2] = { k + (size_t)b * CC * NN, v + (size_t)b * CC * NN };
  const u16* Wp2[2] = { Wb + 36864, Wb + 2 * 36864 };

  f32x4 acc[3][4];
  f32x4 cacc[2][2][2];
  float ksum_r[3][4];
  f32x4 xp[6];       // X prefetch (fp32), single-buffered: read-then-overwrite
  u16x8 wp[3][3];    // W A-frags for current round [ks][et]

#pragma unroll
  for (int hi = 0; hi < 2; ++hi)
#pragma unroll
    for (int mt = 0; mt < 2; ++mt)
#pragma unroll
      for (int nt = 0; nt < 2; ++nt) cacc[hi][mt][nt] = f32x4{0.f, 0.f, 0.f, 0.f};
#pragma unroll
  for (int et = 0; et < 3; ++et)
#pragma unroll
    for (int r = 0; r < 4; ++r) ksum_r[et][r] = 0.f;

  // prologue: issue X loads for round 0 (t=0, pj=0 (K), hf=0)
  {
    const int t0 = blk * 2 * 64;
#pragma unroll
    for (int i = 0; i < 6; ++i) {
      const float* src = xb[0] + (size_t)(scg * 4 + i * 16) * NN + t0 + sn;
      xp[i][0] = src[0]; xp[i][1] = src[NN];
      xp[i][2] = src[2 * NN]; xp[i][3] = src[3 * NN];
    }
  }

#pragma unroll
  for (int r = 0; r < 8; ++r) {
    const int t = r >> 2, pj = (r >> 1) & 1, hf = r & 1;

    // (1) issue W A-frags for THIS round (L2-hot; waited before MFMA only)
#pragma unroll
    for (int ks = 0; ks < 3; ++ks)
#pragma unroll
      for (int et = 0; et < 3; ++et)
        wp[ks][et] = *reinterpret_cast<const u16x8*>(
            &Wp2[pj][(e0 + et * 16 + lc) * 192 + hf * 96 + ks * 32 + lg * 8]);

    // (2) cvt prefetched X -> Xs (hardware inserts the vmcnt wait for xp here)
#pragma unroll
    for (int i = 0; i < 6; ++i) {
      u16x4 pk;
      pk[0] = f2bf(xp[i][0]); pk[1] = f2bf(xp[i][1]);
      pk[2] = f2bf(xp[i][2]); pk[3] = f2bf(xp[i][3]);
      *reinterpret_cast<u16x4*>(&Xs[sn][scg * 4 + i * 16]) = pk;
    }

    // (3) issue NEXT round's X loads — these fly across the barrier + MFMA
    if (r < 7) {
      const int nr = r + 1, nt_ = nr >> 2, npj = (nr >> 1) & 1, nhf = nr & 1;
      const int nt0 = (blk * 2 + nt_) * 64;
#pragma unroll
      for (int i = 0; i < 6; ++i) {
        const float* src = xb[npj] + (size_t)(nhf * 96 + scg * 4 + i * 16) * NN + nt0 + sn;
        xp[i][0] = src[0]; xp[i][1] = src[NN];
        xp[i][2] = src[2 * NN]; xp[i][3] = src[3 * NN];
      }
    }

    // (4) LDS handoff without draining vmcnt
    lgkm_barrier();

    // (5) MFMA
    if (hf == 0) {
#pragma unroll
      for (int et = 0; et < 3; ++et)
#pragma unroll
        for (int nt = 0; nt < 4; ++nt) acc[et][nt] = f32x4{0.f, 0.f, 0.f, 0.f};
    }
#pragma unroll
    for (int ks = 0; ks < 3; ++ks) {
      FragU bb[4];
#pragma unroll
      for (int nt = 0; nt < 4; ++nt)
        bb[nt].u = *reinterpret_cast<const u16x8*>(&Xs[nt * 16 + lc][ks * 32 + lg * 8]);
      FragU aa;
#pragma unroll
      for (int et = 0; et < 3; ++et) {
        aa.u = wp[ks][et];
#pragma unroll
        for (int nt = 0; nt < 4; ++nt)
          acc[et][nt] = __builtin_amdgcn_mfma_f32_16x16x32_bf16(aa.b, bb[nt].b,
                                                               acc[et][nt], 0, 0, 0);
      }
    }

    // (6) epilogues after hf==1
    if (hf == 1 && pj == 0) {
      // K: exp -> Ss, token-sum -> ksum_r  (wave-private rows of Ss)
#pragma unroll
      for (int et = 0; et < 3; ++et)
#pragma unroll
        for (int rr = 0; rr < 4; ++rr) {
          const int e = e0 + et * 16 + lg * 4 + rr;
          const float bias = bk[e];
          float sum = 0.f;
#pragma unroll
          for (int nt = 0; nt < 4; ++nt) {
            const float val = __expf(acc[et][nt][rr] + bias);
            SV[0][e][nt * 16 + lc] = f2bf(val);
            sum += val;
          }
          sum += __shfl_xor(sum, 1);
          sum += __shfl_xor(sum, 2);
          sum += __shfl_xor(sum, 4);
          sum += __shfl_xor(sum, 8);
          ksum_r[et][rr] += sum;
        }
    }
    if (hf == 1 && pj == 1) {
      // V -> Vs; wave-private ctx MFMA (2 k-steps over 64 tokens)
#pragma unroll
      for (int et = 0; et < 3; ++et)
#pragma unroll
        for (int rr = 0; rr < 4; ++rr) {
          const int e = e0 + et * 16 + lg * 4 + rr;
          const float bias = bv[e];
#pragma unroll
          for (int nt = 0; nt < 4; ++nt)
            SV[1][e][nt * 16 + lc] = f2bf(acc[et][nt][rr] + bias);
        }
      // ctx rows are wave-own; cross-wave rows feed only masked dv>=24 outputs
#pragma unroll
      for (int hi = 0; hi < 2; ++hi) {
        const int base = (wave * 2 + hi) * 24;
#pragma unroll
        for (int ks2 = 0; ks2 < 2; ++ks2) {
          FragU av[2], bs[2];
#pragma unroll
          for (int mt = 0; mt < 2; ++mt) {
            int row = base + mt * 16 + lc;
            if (row > 191) row = 191;
            av[mt].u = *reinterpret_cast<const u16x8*>(&SV[1][row][ks2 * 32 + lg * 8]);
            bs[mt].u = *reinterpret_cast<const u16x8*>(&SV[0][row][ks2 * 32 + lg * 8]);
          }
#pragma unroll
          for (int mt = 0; mt < 2; ++mt)
#pragma unroll
            for (int nt = 0; nt < 2; ++nt)
              cacc[hi][mt][nt] = __builtin_amdgcn_mfma_f32_16x16x32_bf16(
                  av[mt].b, bs[nt].b, cacc[hi][mt][nt], 0, 0, 0);
        }
      }
    }

    // (7) all waves done reading Xs before next round's ds_write
    lgkm_barrier();
  }

  // ---- finale: dense coalesced partial store via LDS bounce (reuse SV as Cs) ----
  float* Cs = (float*)&SV[0][0][0];       // 4800 floats = 19.2 KB
#pragma unroll
  for (int hi = 0; hi < 2; ++hi)
#pragma unroll
    for (int mt = 0; mt < 2; ++mt)
#pragma unroll
      for (int nt = 0; nt < 2; ++nt)
#pragma unroll
        for (int rr = 0; rr < 4; ++rr) {
          const int dv = mt * 16 + lg * 4 + rr;
          const int d = nt * 16 + lc;
          if (dv < 24 && d < 24)
            Cs[(wave * 2 + hi) * 576 + dv * 24 + d] = cacc[hi][mt][nt][rr];
        }
  if (lc == 0) {
#pragma unroll
    for (int et = 0; et < 3; ++et)
#pragma unroll
      for (int rr = 0; rr < 4; ++rr) {
        const int e = e0 + et * 16 + lg * 4 + rr;
        Cs[4608 + e] = ksum_r[et][rr];
      }
  }
  lgkm_barrier();
  const size_t pb = (size_t)(b * 128 + blk) * 4800;
#pragma unroll
  for (int rr = 0; rr < 19; ++rr) {
    const int idx = rr * 256 + tid;
    if (idx < 4800) part[pb + idx] = Cs[idx];
  }
}

// Stage-1 reduce: 16 partials -> 1.  part[512][4800] -> part2[32][4800]
__global__ void kr1(const float* __restrict__ part, float* __restrict__ part2)
{
  const int idx = blockIdx.x * 256 + threadIdx.x;   // grid.x = 19
  if (idx >= 4800) return;
  const int gy = blockIdx.y;                        // 0..31 (8 groups per batch)
  float s = 0.f;
#pragma unroll
  for (int j = 0; j < 16; ++j)
    s += part[(size_t)(gy * 16 + j) * 4800 + idx];
  part2[(size_t)gy * 4800 + idx] = s;
}

// Stage-2 reduce + normalize: ctx[b][h][d][dv] = sum(ctx_num) / sum(ksum)
__global__ void kr2(const float* __restrict__ part2, float* __restrict__ ctx)
{
  const int id = blockIdx.x * 256 + threadIdx.x;
  if (id >= 4 * 4608) return;
  const int b = id / 4608, r = id % 4608;
  const int h = r / 576, rem = r % 576;
  const int dv = rem / 24, d = rem % 24;
  float s1 = 0.f, s2 = 0.f;
#pragma unroll
  for (int j = 0; j < 8; ++j) {
    const float* pp = part2 + (size_t)(b * 8 + j) * 4800;
    s1 += pp[h * 576 + dv * 24 + d];
    s2 += pp[4608 + h * 24 + d];
  }
  ctx[((b * 8 + h) * 24 + d) * 24 + dv] = s1 / s2;
}

// Meff[b][o][h*24+d] = sum_dv Wo[o][h*24+dv] * ctx[b][h][d][dv]
__global__ void km(const float* __restrict__ Wo, const float* __restrict__ ctx,
                   u16* __restrict__ Meff)
{
  const int o = blockIdx.x, b = blockIdx.y, j = threadIdx.x;
  const int h = j / 24, d = j % 24;
  const float* Wrow = Wo + o * 192 + h * 24;
  const float* crow = ctx + ((b * 8 + h) * 24 + d) * 24;
  float acc = 0.f;
#pragma unroll
  for (int dv = 0; dv < 24; ++dv) acc += Wrow[dv] * crow[dv];
  Meff[(b * 192 + o) * 192 + j] = f2bf(acc);
}

// One 192x192 (W) @ 192x64 (x fp32->bf16) GEMM for kq.
__device__ __forceinline__ void gemm_stage_compute(
    const float* __restrict__ xb, const u16* __restrict__ Wp,
    int t0, int tid, f32x4 acc[3][4], u16 (*Xs)[QXST])
{
  const int lg = (tid >> 4) & 3, lc = tid & 15;
  const int wave = tid >> 6, e0 = wave * 48;
  const int sn = tid & 63, scg = tid >> 6;
#pragma unroll
  for (int et = 0; et < 3; ++et)
#pragma unroll
    for (int nt = 0; nt < 4; ++nt)
      acc[et][nt] = f32x4{0.f, 0.f, 0.f, 0.f};

#pragma unroll
  for (int hf = 0; hf < 2; ++hf) {
#pragma unroll
    for (int i = 0; i < 6; ++i) {
      int cl = scg * 4 + i * 16;
      const float* src = xb + (size_t)(hf * 96 + cl) * NN + t0 + sn;
      u16x4 p;
      p[0] = f2bf(src[0]);
      p[1] = f2bf(src[NN]);
      p[2] = f2bf(src[2 * NN]);
      p[3] = f2bf(src[3 * NN]);
      *reinterpret_cast<u16x4*>(&Xs[sn][cl]) = p;
    }
    __syncthreads();
#pragma unroll
    for (int ks = 0; ks < 3; ++ks) {
      FragU a[3], bb[4];
#pragma unroll
      for (int et = 0; et < 3; ++et)
        a[et].u = *reinterpret_cast<const u16x8*>(
            &Wp[(e0 + et * 16 + lc) * 192 + hf * 96 + ks * 32 + lg * 8]);
#pragma unroll
      for (int nt = 0; nt < 4; ++nt)
        bb[nt].u = *reinterpret_cast<const u16x8*>(&Xs[nt * 16 + lc][ks * 32 + lg * 8]);
#pragma unroll
      for (int et = 0; et < 3; ++et)
#pragma unroll
        for (int nt = 0; nt < 4; ++nt)
          acc[et][nt] = __builtin_amdgcn_mfma_f32_16x16x32_bf16(a[et].b, bb[nt].b,
                                                               acc[et][nt], 0, 0, 0);
    }
    __syncthreads();
  }
}

// Q kernel: q-proj -> SsT[n][e] -> softmax over d -> Meff GEMM -> out (+bo).
__global__ __launch_bounds__(256, 2)
void kq(const float* __restrict__ q, const u16* __restrict__ Wb,
        const float* __restrict__ bq, const u16* __restrict__ Meff,
        const float* __restrict__ bo, float* __restrict__ out)
{
  __shared__ __align__(16) u16 Xs[64][QXST];
  __shared__ __align__(16) u16 SsT[64][QST];

  const int b = blockIdx.y;
  const int t0 = blockIdx.x * 64;
  const int tid = threadIdx.x;
  const int lg = (tid >> 4) & 3, lc = tid & 15;
  const int wave = tid >> 6, e0 = wave * 48;
  const u16* Mb = Meff + b * 36864;

  f32x4 acc[3][4];

  gemm_stage_compute(q + (size_t)b * CC * NN, Wb, t0, tid, acc, Xs);
#pragma unroll
  for (int et = 0; et < 3; ++et)
#pragma unroll
    for (int r = 0; r < 4; ++r) {
      int e = e0 + et * 16 + lg * 4 + r;
      float bias = bq[e];
#pragma unroll
      for (int nt = 0; nt < 4; ++nt)
        SsT[nt * 16 + lc][e] = f2bf(acc[et][nt][r] + bias);
    }
  __syncthreads();

#pragma unroll
  for (int ii = 0; ii < 2; ++ii) {
    const int item = ii * 256 + tid;
    const int n = item & 63, h = item >> 6;
    u16* rowp = &SsT[n][h * 24];
    float vals[24];
    float m = -1e30f;
#pragma unroll
    for (int d = 0; d < 24; ++d) {
      vals[d] = bf2f(rowp[d]);
      m = fmaxf(m, vals[d]);
    }
    float s = 0.f;
#pragma unroll
    for (int d = 0; d < 24; ++d) { vals[d] = __expf(vals[d] - m); s += vals[d]; }
    const float inv = 1.f / s;
#pragma unroll
    for (int d = 0; d < 24; ++d) rowp[d] = f2bf(vals[d] * inv);
  }
  __syncthreads();

#pragma unroll
  for (int et = 0; et < 3; ++et)
#pragma unroll
    for (int nt = 0; nt < 4; ++nt) acc[et][nt] = f32x4{0.f, 0.f, 0.f, 0.f};
#pragma unroll
  for (int ks = 0; ks < 6; ++ks) {
    FragU a[3], bb[4];
#pragma unroll
    for (int et = 0; et < 3; ++et)
      a[et].u = *reinterpret_cast<const u16x8*>(
          &Mb[(e0 + et * 16 + lc) * 192 + ks * 32 + lg * 8]);
#pragma unroll
    for (int nt = 0; nt < 4; ++nt)
      bb[nt].u = *reinterpret_cast<const u16x8*>(&SsT[nt * 16 + lc][ks * 32 + lg * 8]);
#pragma unroll
    for (int et = 0; et < 3; ++et)
#pragma unroll
      for (int nt = 0; nt < 4; ++nt)
        acc[et][nt] = __builtin_amdgcn_mfma_f32_16x16x32_bf16(a[et].b, bb[nt].b,
                                                             acc[et][nt], 0, 0, 0);
  }

#pragma unroll
  for (int et = 0; et < 3; ++et)
#pragma unroll
    for (int r = 0; r < 4; ++r) {
      int row = e0 + et * 16 + lg * 4 + r;
      float bias = bo[row];
#pragma unroll
      for (int nt = 0; nt < 4; ++nt)
        out[(size_t)(b * 192 + row) * NN + t0 + nt * 16 + lc] = acc[et][nt][r] + bias;
    }
}

// Convert Wq/Wk/Wv to bf16 (packed [3][192][192]).
__global__ void kz(const float* __restrict__ Wq, const float* __restrict__ Wk,
                   const float* __restrict__ Wv, u16* __restrict__ Wb)
{
  const int i = blockIdx.x * 256 + threadIdx.x;
  if (i < 110592) {
    const float* src = (i < 36864) ? Wq : (i < 73728) ? Wk : Wv;
    Wb[i] = f2bf(src[i % 36864]);
  }
}

extern "C" void kernel_launch(void* const* d_in, const int* in_sizes, int n_in,
                              void* d_out, int out_size, void* d_ws, size_t ws_size,
                              hipStream_t stream)
{
  const float* q  = (const float*)d_in[0];
  const float* k  = (const float*)d_in[1];
  const float* v  = (const float*)d_in[2];
  const float* Wq = (const float*)d_in[3];
  const float* bq = (const float*)d_in[4];
  const float* Wk = (const float*)d_in[5];
  const float* bk = (const float*)d_in[6];
  const float* Wv = (const float*)d_in[7];
  const float* bv = (const float*)d_in[8];
  const float* Wo = (const float*)d_in[9];
  const float* bo = (const float*)d_in[10];
  float* out = (float*)d_out;

  // workspace carve (256B-aligned); total ~11.0 MB
  char* w = (char*)d_ws;
  u16*   Wb    = (u16*)(w);                    // 221184 B : [3][192][192] bf16
  float* part  = (float*)(w + 221184);         // 9830400 B : [512][4800]
  float* part2 = (float*)(w + 10051584);       // 614400 B : [32][4800]
  float* ctx   = (float*)(w + 10665984);       // 73728 B : [4][8][24][24]
  u16*   Meff  = (u16*)(w + 10739712);         // 294912 B : [4][192][192] bf16

  hipLaunchKernelGGL(kz, dim3(432), dim3(256), 0, stream, Wq, Wk, Wv, Wb);
  hipLaunchKernelGGL(kv, dim3(128, 4), dim3(256), 0, stream, k, v, Wb, bk, bv, part);
  hipLaunchKernelGGL(kr1, dim3(19, 32), dim3(256), 0, stream, part, part2);
  hipLaunchKernelGGL(kr2, dim3(72), dim3(256), 0, stream, part2, ctx);
  hipLaunchKernelGGL(km, dim3(192, 4), dim3(192), 0, stream, Wo, ctx, Meff);
  hipLaunchKernelGGL(kq, dim3(256, 4), dim3(256), 0, stream, q, Wb, bq, Meff, bo, out);
}

// Round 7
// 100.292 us; speedup vs baseline: 1.6024x; 1.6024x over previous
//
#include <hip/hip_runtime.h>

#define CC 192
#define NN 16384
#define QXST 104  // staging LDS stride (elems)
#define QST 200   // kq SsT stride

typedef unsigned short u16;
typedef __attribute__((ext_vector_type(4))) float f32x4;
typedef __attribute__((ext_vector_type(8))) __bf16 bf16x8;
typedef __attribute__((ext_vector_type(8))) u16 u16x8;
typedef __attribute__((ext_vector_type(4))) u16 u16x4;

union FragU { u16x8 u; bf16x8 b; };

__device__ __forceinline__ u16 f2bf(float f) {
  union { float f; unsigned u; } x; x.f = f;
  return (u16)((x.u + 0x7FFFu + ((x.u >> 16) & 1u)) >> 16);  // RNE
}
__device__ __forceinline__ float bf2f(u16 h) {
  union { unsigned u; float f; } x; x.u = ((unsigned)h) << 16;
  return x.f;
}

// One 192x192 (W, bf16) @ 192x64 (x, fp32->bf16) GEMM into per-wave acc[3][4].
// Wave w owns output rows [48w,48w+48). MFMA 16x16x32 bf16.
__device__ __forceinline__ void gemm_stage_compute(
    const float* __restrict__ xb, const u16* __restrict__ Wp,
    int t0, int tid, f32x4 acc[3][4], u16 (*Xs)[QXST])
{
  const int lg = (tid >> 4) & 3, lc = tid & 15;
  const int wave = tid >> 6, e0 = wave * 48;
  const int sn = tid & 63, scg = tid >> 6;
#pragma unroll
  for (int et = 0; et < 3; ++et)
#pragma unroll
    for (int nt = 0; nt < 4; ++nt)
      acc[et][nt] = f32x4{0.f, 0.f, 0.f, 0.f};

#pragma unroll
  for (int hf = 0; hf < 2; ++hf) {
#pragma unroll
    for (int i = 0; i < 6; ++i) {
      int cl = scg * 4 + i * 16;
      const float* src = xb + (size_t)(hf * 96 + cl) * NN + t0 + sn;
      u16x4 p;
      p[0] = f2bf(src[0]);
      p[1] = f2bf(src[NN]);
      p[2] = f2bf(src[2 * NN]);
      p[3] = f2bf(src[3 * NN]);
      *reinterpret_cast<u16x4*>(&Xs[sn][cl]) = p;
    }
    __syncthreads();
#pragma unroll
    for (int ks = 0; ks < 3; ++ks) {
      FragU a[3], bb[4];
#pragma unroll
      for (int et = 0; et < 3; ++et)
        a[et].u = *reinterpret_cast<const u16x8*>(
            &Wp[(e0 + et * 16 + lc) * 192 + hf * 96 + ks * 32 + lg * 8]);
#pragma unroll
      for (int nt = 0; nt < 4; ++nt)
        bb[nt].u = *reinterpret_cast<const u16x8*>(&Xs[nt * 16 + lc][ks * 32 + lg * 8]);
#pragma unroll
      for (int et = 0; et < 3; ++et)
#pragma unroll
        for (int nt = 0; nt < 4; ++nt)
          acc[et][nt] = __builtin_amdgcn_mfma_f32_16x16x32_bf16(a[et].b, bb[nt].b,
                                                               acc[et][nt], 0, 0, 0);
    }
    __syncthreads();
  }
}

// K/V projection: one 64-token tile of one projection per block.
// z=0: Sexp = exp(Wk@k + bk)  (bf16);  z=1: Vb = Wv@v + bv  (bf16).
__global__ __launch_bounds__(256, 2)
void kproj(const float* __restrict__ k, const float* __restrict__ v,
           const u16* __restrict__ Wb, const float* __restrict__ bk,
           const float* __restrict__ bv, u16* __restrict__ Sexp,
           u16* __restrict__ Vbuf)
{
  __shared__ __align__(16) u16 Xs[64][QXST];   // 13.3 KB only
  const int b = blockIdx.y, pj = blockIdx.z;
  const int t0 = blockIdx.x * 64;
  const int tid = threadIdx.x;
  const int lg = (tid >> 4) & 3, lc = tid & 15;
  const int wave = tid >> 6, e0 = wave * 48;

  const float* xb = (pj ? v : k) + (size_t)b * CC * NN;
  const u16* Wp = Wb + (pj ? 2 : 1) * 36864;
  const float* bias = pj ? bv : bk;
  u16* outp = pj ? Vbuf : Sexp;

  f32x4 acc[3][4];
  gemm_stage_compute(xb, Wp, t0, tid, acc, Xs);

#pragma unroll
  for (int et = 0; et < 3; ++et)
#pragma unroll
    for (int r = 0; r < 4; ++r) {
      const int e = e0 + et * 16 + lg * 4 + r;
      const float bb = bias[e];
      u16* orow = outp + (size_t)(b * 192 + e) * NN + t0;
#pragma unroll
      for (int nt = 0; nt < 4; ++nt) {
        float val = acc[et][nt][r] + bb;
        if (!pj) val = __expf(val);        // |kp| small; no max-sub needed
        orow[nt * 16 + lc] = f2bf(val);
      }
    }
}

// ctx partials: block = (slab of 128 tokens, batch); 8 waves, wave = head.
// cacc[mt][nt] += V[dv rows] @ S[d rows]^T over 4 k-steps. No LDS, no barriers.
__global__ __launch_bounds__(512, 2)
void kctx(const u16* __restrict__ Sexp, const u16* __restrict__ Vbuf,
          float* __restrict__ part)
{
  const int b = blockIdx.y, slab = blockIdx.x;   // 128 slabs x 128 tokens
  const int tid = threadIdx.x;
  const int h = tid >> 6;
  const int lg = (tid >> 4) & 3, lc = tid & 15;
  const int n0 = slab * 128;
  const size_t basee = (size_t)b * 192 * NN;

  f32x4 cacc[2][2];
#pragma unroll
  for (int mt = 0; mt < 2; ++mt)
#pragma unroll
    for (int nt = 0; nt < 2; ++nt) cacc[mt][nt] = f32x4{0.f, 0.f, 0.f, 0.f};

#pragma unroll
  for (int ks = 0; ks < 4; ++ks) {
    const int tok = n0 + ks * 32 + lg * 8;
    FragU av[2], bs[2];
#pragma unroll
    for (int mt = 0; mt < 2; ++mt) {
      int row = h * 24 + mt * 16 + lc;   // rows >= h*24+24 feed masked outputs
      if (row > 191) row = 191;
      av[mt].u = *reinterpret_cast<const u16x8*>(&Vbuf[basee + (size_t)row * NN + tok]);
      bs[mt].u = *reinterpret_cast<const u16x8*>(&Sexp[basee + (size_t)row * NN + tok]);
    }
#pragma unroll
    for (int mt = 0; mt < 2; ++mt)
#pragma unroll
      for (int nt = 0; nt < 2; ++nt)
        cacc[mt][nt] = __builtin_amdgcn_mfma_f32_16x16x32_bf16(
            av[mt].b, bs[nt].b, cacc[mt][nt], 0, 0, 0);
  }

  // part[b][slab][h][dv*24+d]
  float* pp = part + (((size_t)(b * 128 + slab)) * 8 + h) * 576;
#pragma unroll
  for (int mt = 0; mt < 2; ++mt)
#pragma unroll
    for (int nt = 0; nt < 2; ++nt)
#pragma unroll
      for (int r = 0; r < 4; ++r) {
        const int dv = mt * 16 + lg * 4 + r;
        const int d = nt * 16 + lc;
        if (dv < 24 && d < 24) pp[dv * 24 + d] = cacc[mt][nt][r];
      }
}

// ksum[row] = sum_n Sexp[row][n]   (row = b*192 + e)
__global__ __launch_bounds__(256, 2)
void krow(const u16* __restrict__ Sexp, float* __restrict__ ksum)
{
  __shared__ float red[4];
  const int row = blockIdx.x;
  const int tid = threadIdx.x;
  const u16* p = Sexp + (size_t)row * NN;
  float s = 0.f;
#pragma unroll
  for (int i = 0; i < 8; ++i) {
    u16x8 vv = *reinterpret_cast<const u16x8*>(&p[(i * 256 + tid) * 8]);
#pragma unroll
    for (int j = 0; j < 8; ++j) s += bf2f(vv[j]);
  }
#pragma unroll
  for (int off = 1; off < 64; off <<= 1) s += __shfl_xor(s, off);
  if ((tid & 63) == 0) red[tid >> 6] = s;
  __syncthreads();
  if (tid == 0) ksum[row] = red[0] + red[1] + red[2] + red[3];
}

// Reduce 128 slab partials + normalize: ctx[b][h*576 + dv*24 + d]
__global__ void kr2(const float* __restrict__ part, const float* __restrict__ ksum,
                    float* __restrict__ ctx)
{
  const int idx = blockIdx.x * 256 + threadIdx.x;   // 0..4607
  if (idx >= 4608) return;
  const int b = blockIdx.y;
  const int h = idx / 576, rem = idx % 576;
  const int d = rem % 24;
  float s = 0.f;
  const float* pp = part + (size_t)b * 128 * 4608 + idx;
#pragma unroll 8
  for (int j = 0; j < 128; ++j) s += pp[(size_t)j * 4608];
  ctx[(size_t)b * 4608 + idx] = s / ksum[b * 192 + h * 24 + d];
}

// Meff[b][o][h*24+d] = sum_dv Wo[o][h*24+dv] * ctx[b][h][dv*24+d]
__global__ void km(const float* __restrict__ Wo, const float* __restrict__ ctx,
                   u16* __restrict__ Meff)
{
  const int o = blockIdx.x, b = blockIdx.y, j = threadIdx.x;
  const int h = j / 24, d = j % 24;
  const float* Wrow = Wo + o * 192 + h * 24;
  const float* crow = ctx + (size_t)b * 4608 + h * 576 + d;   // stride 24 over dv
  float acc = 0.f;
#pragma unroll
  for (int dv = 0; dv < 24; ++dv) acc += Wrow[dv] * crow[dv * 24];
  Meff[(b * 192 + o) * 192 + j] = f2bf(acc);
}

// Q kernel: q-proj -> SsT[n][e] -> softmax over d -> Meff GEMM -> out (+bo).
__global__ __launch_bounds__(256, 2)
void kq(const float* __restrict__ q, const u16* __restrict__ Wb,
        const float* __restrict__ bq, const u16* __restrict__ Meff,
        const float* __restrict__ bo, float* __restrict__ out)
{
  __shared__ __align__(16) u16 Xs[64][QXST];
  __shared__ __align__(16) u16 SsT[64][QST];

  const int b = blockIdx.y;
  const int t0 = blockIdx.x * 64;
  const int tid = threadIdx.x;
  const int lg = (tid >> 4) & 3, lc = tid & 15;
  const int wave = tid >> 6, e0 = wave * 48;
  const u16* Mb = Meff + b * 36864;

  f32x4 acc[3][4];

  gemm_stage_compute(q + (size_t)b * CC * NN, Wb, t0, tid, acc, Xs);
#pragma unroll
  for (int et = 0; et < 3; ++et)
#pragma unroll
    for (int r = 0; r < 4; ++r) {
      int e = e0 + et * 16 + lg * 4 + r;
      float bias = bq[e];
#pragma unroll
      for (int nt = 0; nt < 4; ++nt)
        SsT[nt * 16 + lc][e] = f2bf(acc[et][nt][r] + bias);
    }
  __syncthreads();

#pragma unroll
  for (int ii = 0; ii < 2; ++ii) {
    const int item = ii * 256 + tid;
    const int n = item & 63, h = item >> 6;
    u16* rowp = &SsT[n][h * 24];
    float vals[24];
    float m = -1e30f;
#pragma unroll
    for (int d = 0; d < 24; ++d) {
      vals[d] = bf2f(rowp[d]);
      m = fmaxf(m, vals[d]);
    }
    float s = 0.f;
#pragma unroll
    for (int d = 0; d < 24; ++d) { vals[d] = __expf(vals[d] - m); s += vals[d]; }
    const float inv = 1.f / s;
#pragma unroll
    for (int d = 0; d < 24; ++d) rowp[d] = f2bf(vals[d] * inv);
  }
  __syncthreads();

#pragma unroll
  for (int et = 0; et < 3; ++et)
#pragma unroll
    for (int nt = 0; nt < 4; ++nt) acc[et][nt] = f32x4{0.f, 0.f, 0.f, 0.f};
#pragma unroll
  for (int ks = 0; ks < 6; ++ks) {
    FragU a[3], bb[4];
#pragma unroll
    for (int et = 0; et < 3; ++et)
      a[et].u = *reinterpret_cast<const u16x8*>(
          &Mb[(e0 + et * 16 + lc) * 192 + ks * 32 + lg * 8]);
#pragma unroll
    for (int nt = 0; nt < 4; ++nt)
      bb[nt].u = *reinterpret_cast<const u16x8*>(&SsT[nt * 16 + lc][ks * 32 + lg * 8]);
#pragma unroll
    for (int et = 0; et < 3; ++et)
#pragma unroll
      for (int nt = 0; nt < 4; ++nt)
        acc[et][nt] = __builtin_amdgcn_mfma_f32_16x16x32_bf16(a[et].b, bb[nt].b,
                                                             acc[et][nt], 0, 0, 0);
  }

#pragma unroll
  for (int et = 0; et < 3; ++et)
#pragma unroll
    for (int r = 0; r < 4; ++r) {
      int row = e0 + et * 16 + lg * 4 + r;
      float bias = bo[row];
#pragma unroll
      for (int nt = 0; nt < 4; ++nt)
        out[(size_t)(b * 192 + row) * NN + t0 + nt * 16 + lc] = acc[et][nt][r] + bias;
    }
}

// Convert Wq/Wk/Wv to bf16 (packed [3][192][192]).
__global__ void kz(const float* __restrict__ Wq, const float* __restrict__ Wk,
                   const float* __restrict__ Wv, u16* __restrict__ Wb)
{
  const int i = blockIdx.x * 256 + threadIdx.x;
  if (i < 110592) {
    const float* src = (i < 36864) ? Wq : (i < 73728) ? Wk : Wv;
    Wb[i] = f2bf(src[i % 36864]);
  }
}

extern "C" void kernel_launch(void* const* d_in, const int* in_sizes, int n_in,
                              void* d_out, int out_size, void* d_ws, size_t ws_size,
                              hipStream_t stream)
{
  const float* q  = (const float*)d_in[0];
  const float* k  = (const float*)d_in[1];
  const float* v  = (const float*)d_in[2];
  const float* Wq = (const float*)d_in[3];
  const float* bq = (const float*)d_in[4];
  const float* Wk = (const float*)d_in[5];
  const float* bk = (const float*)d_in[6];
  const float* Wv = (const float*)d_in[7];
  const float* bv = (const float*)d_in[8];
  const float* Wo = (const float*)d_in[9];
  const float* bo = (const float*)d_in[10];
  float* out = (float*)d_out;

  // workspace carve (256B-aligned); total ~60.4 MB
  char* w = (char*)d_ws;
  u16*   Wb   = (u16*)(w);                     // 221184 B : [3][192][192] bf16
  u16*   Sexp = (u16*)(w + 221184);            // 25165824 B : [4][192][16384] bf16
  u16*   Vbuf = (u16*)(w + 25387008);          // 25165824 B : [4][192][16384] bf16
  float* part = (float*)(w + 50552832);        // 9437184 B : [4][128][8][576]
  float* ksum = (float*)(w + 59990016);        // 3072 B : [4][192]
  float* ctx  = (float*)(w + 59993088);        // 73728 B : [4][8][576]
  u16*   Meff = (u16*)(w + 60066816);          // 294912 B : [4][192][192] bf16

  hipLaunchKernelGGL(kz, dim3(432), dim3(256), 0, stream, Wq, Wk, Wv, Wb);
  hipLaunchKernelGGL(kproj, dim3(256, 4, 2), dim3(256), 0, stream,
                     k, v, Wb, bk, bv, Sexp, Vbuf);
  hipLaunchKernelGGL(krow, dim3(768), dim3(256), 0, stream, Sexp, ksum);
  hipLaunchKernelGGL(kctx, dim3(128, 4), dim3(512), 0, stream, Sexp, Vbuf, part);
  hipLaunchKernelGGL(kr2, dim3(18, 4), dim3(256), 0, stream, part, ksum, ctx);
  hipLaunchKernelGGL(km, dim3(192, 4), dim3(192), 0, stream, Wo, ctx, Meff);
  hipLaunchKernelGGL(kq, dim3(256, 4), dim3(256), 0, stream, q, Wb, bq, Meff, bo, out);
}